// Round 4
// baseline (523.290 us; speedup 1.0000x reference)
//
#include <hip/hip_runtime.h>
#include <stdint.h>

// ---------------------------------------------------------------------------
// NonLocalBlockND: B=8, C_IN=256, C_INTER=128, H=W=128, P=16 -> tokens 256/batch,
// token dim D = 128*64 = 8192 (d = c*64 + s, s = u*8+v within 8x8 patch).
// Pipeline:
//   K1 prep   : weights -> bf16; theta/phi/g pre-swizzled into MFMA A-fragment
//               order; hi+lo split for theta/phi
//   K2 proj   : persistent 8-token blocks; weights REGISTER-RESIDENT per wave
//               (theta-or-phi slice hi/lo + g slice); x staged hi/lo in 64KB
//               LDS per token; inner loop = 2 ds_read_b128 -> 8 MFMA.
//               Grid 256 (1 block/CU), XCD-chunked (block phys -> batch phys&7).
//   K3 qk     : f = theta . phi (3-term bf16 split MFMA), K-split 16, partials in ws
//   K4 softmax: reduce partials, softmax rows -> p (bf16)
//   K5 pv     : y = p . g (bf16 MFMA) -> d_out (theta/phi dead)
//   K6 wconv  : w_y = y . w_w + w_b (bf16 MFMA), pixel-major bf16 + BN stats atomics
//   K7 final  : out = (w_y - mean)*rsqrt(var+eps)*gamma + beta + x   (fp32)
// ---------------------------------------------------------------------------

typedef unsigned short u16t;
typedef short s16x8 __attribute__((ext_vector_type(8)));
typedef float f32x4 __attribute__((ext_vector_type(4)));
typedef uint32_t u32x4 __attribute__((ext_vector_type(4)));

#define DEV __device__ __forceinline__

DEV u16t f2bf(float f) {
    union { float f; uint32_t u; } v; v.f = f;
    return (u16t)((v.u + 0x7FFFu + ((v.u >> 16) & 1u)) >> 16);
}
DEV float bf2f(u16t h) {
    union { uint32_t u; float f; } v; v.u = ((uint32_t)h) << 16; return v.f;
}
DEV f32x4 MFMA(s16x8 a, s16x8 b, f32x4 c) {
    return __builtin_amdgcn_mfma_f32_16x16x32_bf16(a, b, c, 0, 0, 0);
}
DEV s16x8 gather8(const u16t* base, int stride) {
    s16x8 r;
#pragma unroll
    for (int j = 0; j < 8; ++j) r[j] = (short)base[j * stride];
    return r;
}

// ---------------- K1: weight prep -> bf16 ------------------------------------
// th/tl/ph/pl/g stored A-fragment-swizzled: for o in [0,128), c in [0,256):
//   fi = ((o>>4)*8 + (c>>5))*512 + (((c>>3)&3)*16 + (o&15))*8 + (c&7)
// so the A-load for (rt,kk) is 64 lanes x 16B contiguous.
// wcv (w_w, [256][128]) kept flat at 163840.
__global__ void __launch_bounds__(256) k_prep(
    const float* __restrict__ gw, const float* __restrict__ tw,
    const float* __restrict__ pw, const float* __restrict__ ww,
    u16t* __restrict__ wb)
{
    int i = blockIdx.x * 256 + threadIdx.x;
    if (i >= 32768) return;
    int o = i >> 8, c = i & 255;
    int fi = ((o >> 4) * 8 + (c >> 5)) * 512 + (((c >> 3) & 3) * 16 + (o & 15)) * 8 + (c & 7);
    float t = tw[i], p = pw[i];
    u16t th = f2bf(t); u16t tl = f2bf(t - bf2f(th));
    u16t ph = f2bf(p); u16t pl = f2bf(p - bf2f(ph));
    wb[fi] = th; wb[32768 + fi] = tl;
    wb[65536 + fi] = ph; wb[98304 + fi] = pl;
    wb[131072 + fi] = f2bf(gw[i]);
    wb[163840 + i] = f2bf(ww[i]);
}

// ---------------- K2: projections, weight-resident persistent blocks --------
// Block = 8 waves (512 thr), processes 8 consecutive tokens of one batch.
// Wave w: theta (w<4) or phi (w>=4), o-slice [32*(w&3), +32) hi+lo resident
// (32 s16x8) + g o-slice [16*w, +16) hi resident (8 s16x8). Per token, x is
// staged hi/lo into 64KB LDS ([pix][256c], octet rot-swizzle); inner loop per
// (kk,ct): 2 ds_read_b128 -> 8 MFMA (theta q0,q1 x3-term; g x2-term).
__global__ void __launch_bounds__(512, 2) k_proj(
    const float* __restrict__ x, const u16t* __restrict__ wb,
    const float* __restrict__ tb, const float* __restrict__ pb, const float* __restrict__ gbias,
    float* __restrict__ out_t, float* __restrict__ out_p, u16t* __restrict__ out_g)
{
    __shared__ u16t xh[64 * 256];
    __shared__ u16t xl[64 * 256];
    int phys = blockIdx.x;
    int blk = ((phys & 7) << 5) + (phys >> 3);   // XCD chunk: batch (phys&7) per XCD
    int b = blk >> 5;
    int tbase = (blk & 31) * 8;                  // token n base within batch
    int t = threadIdx.x;
    int w = t >> 6, l = t & 63, lr = l & 15, lg = l >> 4;

    // ---- resident weights
    int isphi = w >> 2;
    int slice = w & 3;
    const u16t* Wh = wb + isphi * 65536;
    const u16t* Wl = Wh + 32768;
    const u16t* Wg = wb + 131072;
    s16x8 wh0[8], wh1[8], wl0[8], wl1[8], gh[8];
#pragma unroll
    for (int kk = 0; kk < 8; ++kk) {
        wh0[kk] = *(const s16x8*)(Wh + (size_t)(((2 * slice + 0) * 8 + kk) * 64 + l) * 8);
        wh1[kk] = *(const s16x8*)(Wh + (size_t)(((2 * slice + 1) * 8 + kk) * 64 + l) * 8);
        wl0[kk] = *(const s16x8*)(Wl + (size_t)(((2 * slice + 0) * 8 + kk) * 64 + l) * 8);
        wl1[kk] = *(const s16x8*)(Wl + (size_t)(((2 * slice + 1) * 8 + kk) * 64 + l) * 8);
        gh[kk]  = *(const s16x8*)(Wg + (size_t)((w * 8 + kk) * 64 + l) * 8);
    }
    const float* biasT = isphi ? pb : tb;
    float* outT = isphi ? out_p : out_t;

    int pixs = t >> 3, og = t & 7;               // staging: thread = (pixel, octet-group)

    for (int tt = 0; tt < 8; ++tt) {
        int n = tbase + tt;
        int pi = n >> 4, pj = n & 15;
        // ---- stage x hi/lo for this token
        const float* xb = x + (((size_t)b * 256) * 128 + pi * 8 + (pixs >> 3)) * 128 + pj * 8 + (pixs & 7);
        float xv[4][8];
#pragma unroll
        for (int i = 0; i < 4; ++i)
#pragma unroll
            for (int j = 0; j < 8; ++j)
                xv[i][j] = xb[(size_t)((og * 4 + i) * 8 + j) * 16384];
#pragma unroll
        for (int i = 0; i < 4; ++i) {
            int octet = og * 4 + i;
            u32x4 hv, lv;
#pragma unroll
            for (int j = 0; j < 8; j += 2) {
                uint32_t u0 = __float_as_uint(xv[i][j]), u1 = __float_as_uint(xv[i][j + 1]);
                hv[j >> 1] = (u0 >> 16) | (u1 & 0xFFFF0000u);          // truncation hi
                float f0 = xv[i][j]     - __uint_as_float(u0 & 0xFFFF0000u);
                float f1 = xv[i][j + 1] - __uint_as_float(u1 & 0xFFFF0000u);
                lv[j >> 1] = (uint32_t)f2bf(f0) | ((uint32_t)f2bf(f1) << 16);  // RN lo
            }
            int oct2 = (octet + pixs) & 31;
            *(s16x8*)(xh + pixs * 256 + oct2 * 8) = __builtin_bit_cast(s16x8, hv);
            *(s16x8*)(xl + pixs * 256 + oct2 * 8) = __builtin_bit_cast(s16x8, lv);
        }
        __syncthreads();

        // ---- compute: all weights in regs, only LDS reads in the loop
        f32x4 at0[4], at1[4], ag[4];
#pragma unroll
        for (int ct = 0; ct < 4; ++ct) {
            at0[ct] = (f32x4){0.f, 0.f, 0.f, 0.f};
            at1[ct] = (f32x4){0.f, 0.f, 0.f, 0.f};
            ag[ct]  = (f32x4){0.f, 0.f, 0.f, 0.f};
        }
#pragma unroll
        for (int kk = 0; kk < 8; ++kk) {
#pragma unroll
            for (int ct = 0; ct < 4; ++ct) {
                int pr = ct * 16 + lr;
                int rot = (kk * 4 + lg + pr) & 31;
                s16x8 bh = *(const s16x8*)(xh + pr * 256 + rot * 8);
                s16x8 bl = *(const s16x8*)(xl + pr * 256 + rot * 8);
                at0[ct] = MFMA(wh0[kk], bh, at0[ct]);
                at1[ct] = MFMA(wh1[kk], bh, at1[ct]);
                ag[ct]  = MFMA(gh[kk],  bh, ag[ct]);
                at0[ct] = MFMA(wl0[kk], bh, at0[ct]);
                at1[ct] = MFMA(wl1[kk], bh, at1[ct]);
                at0[ct] = MFMA(wh0[kk], bl, at0[ct]);
                at1[ct] = MFMA(wh1[kk], bl, at1[ct]);
                ag[ct]  = MFMA(gh[kk],  bl, ag[ct]);
            }
        }

        // ---- epilogue
        size_t obase = ((size_t)b * 256 + n) * 8192;
#pragma unroll
        for (int q = 0; q < 2; ++q) {
#pragma unroll
            for (int r = 0; r < 4; ++r) {
                int o = slice * 32 + q * 16 + lg * 4 + r;
                float bv = biasT[o];
#pragma unroll
                for (int ct = 0; ct < 4; ++ct) {
                    float v = (q ? at1[ct][r] : at0[ct][r]) + bv;
                    outT[obase + (size_t)o * 64 + ct * 16 + lr] = v;
                }
            }
        }
#pragma unroll
        for (int r = 0; r < 4; ++r) {
            int o = w * 16 + lg * 4 + r;
            float bv = gbias[o];
#pragma unroll
            for (int ct = 0; ct < 4; ++ct)
                out_g[obase + (size_t)o * 64 + ct * 16 + lr] = f2bf(ag[ct][r] + bv);
        }
        __syncthreads();   // all waves done reading LDS before next stage
    }
}

// ---------------- K3: QK^T, 3-term split, K-split 16 -------------------------
// grid 512: mt=blk&1, nt=(blk>>1)&1, b=(blk>>2)&7, kc=blk>>5 ; tile 128x128, BK=32
__global__ void __launch_bounds__(256) k_qk(
    const float* __restrict__ th_g, const float* __restrict__ ph_g, float* __restrict__ fp)
{
    __shared__ u16t th[128 * 40], tl[128 * 40], ph[128 * 40], pl[128 * 40];
    int blk = blockIdx.x;
    int mt = blk & 1, nt = (blk >> 1) & 1, b = (blk >> 2) & 7, kc = blk >> 5;
    int n0 = nt * 128, m0 = mt * 128;
    int t = threadIdx.x;
    int w = t >> 6, l = t & 63, lr = l & 15, lg = l >> 4;
    int wn = (w & 1) * 64, wm = (w >> 1) * 64;
    f32x4 acc[4][4];
#pragma unroll
    for (int i = 0; i < 4; ++i)
#pragma unroll
        for (int j = 0; j < 4; ++j) acc[i][j] = (f32x4){0.f, 0.f, 0.f, 0.f};

    const float* tsrc = th_g + ((size_t)b * 256 + n0) * 8192 + kc * 512;
    const float* psrc = ph_g + ((size_t)b * 256 + m0) * 8192 + kc * 512;

    for (int kk = 0; kk < 16; ++kk) {
        __syncthreads();
        // stage 256 rows (theta 0-127, phi 128-255) x 32 d, 8 threads/row
#pragma unroll
        for (int i = 0; i < 8; ++i) {
            int row = i * 32 + (t >> 3);
            int q = t & 7;
            int r7 = row & 127;
            const float* sp = ((row < 128) ? (tsrc + (size_t)r7 * 8192)
                                           : (psrc + (size_t)r7 * 8192)) + kk * 32 + q * 4;
            float4 v = *(const float4*)sp;
            u16t* dh = ((row < 128) ? th : ph) + r7 * 40 + q * 4;
            u16t* dl = ((row < 128) ? tl : pl) + r7 * 40 + q * 4;
            u16t h0 = f2bf(v.x), h1 = f2bf(v.y), h2 = f2bf(v.z), h3 = f2bf(v.w);
            *(ushort2*)dh       = make_ushort2(h0, h1);
            *(ushort2*)(dh + 2) = make_ushort2(h2, h3);
            *(ushort2*)dl       = make_ushort2(f2bf(v.x - bf2f(h0)), f2bf(v.y - bf2f(h1)));
            *(ushort2*)(dl + 2) = make_ushort2(f2bf(v.z - bf2f(h2)), f2bf(v.w - bf2f(h3)));
        }
        __syncthreads();
        s16x8 a_h[4], a_l[4], b_h[4], b_l[4];
#pragma unroll
        for (int rt = 0; rt < 4; ++rt) {
            int row = wn + rt * 16 + lr;
            a_h[rt] = *(const s16x8*)(th + row * 40 + lg * 8);
            a_l[rt] = *(const s16x8*)(tl + row * 40 + lg * 8);
        }
#pragma unroll
        for (int ct = 0; ct < 4; ++ct) {
            int row = wm + ct * 16 + lr;
            b_h[ct] = *(const s16x8*)(ph + row * 40 + lg * 8);
            b_l[ct] = *(const s16x8*)(pl + row * 40 + lg * 8);
        }
#pragma unroll
        for (int rt = 0; rt < 4; ++rt)
#pragma unroll
            for (int ct = 0; ct < 4; ++ct) {
                acc[rt][ct] = MFMA(a_h[rt], b_h[ct], acc[rt][ct]);
                acc[rt][ct] = MFMA(a_l[rt], b_h[ct], acc[rt][ct]);
                acc[rt][ct] = MFMA(a_h[rt], b_l[ct], acc[rt][ct]);
            }
    }
    float* dst = fp + (size_t)kc * 524288 + ((size_t)b * 256 + n0 + wn) * 256 + m0 + wm;
#pragma unroll
    for (int rt = 0; rt < 4; ++rt)
#pragma unroll
        for (int r = 0; r < 4; ++r) {
            int nn = rt * 16 + lg * 4 + r;
#pragma unroll
            for (int ct = 0; ct < 4; ++ct)
                dst[(size_t)nn * 256 + ct * 16 + lr] = acc[rt][ct][r];
        }
}

// ---------------- K4: reduce partials + row softmax -> p bf16 ---------------
__global__ void __launch_bounds__(256) k_softmax(
    const float* __restrict__ fp, u16t* __restrict__ pout)
{
    int row = blockIdx.x * 4 + (threadIdx.x >> 6);
    int l = threadIdx.x & 63;
    const float* src = fp + (size_t)row * 256 + l * 4;
    float4 s = {0.f, 0.f, 0.f, 0.f};
#pragma unroll
    for (int kc = 0; kc < 16; ++kc) {
        float4 v = *(const float4*)(src + (size_t)kc * 524288);
        s.x += v.x; s.y += v.y; s.z += v.z; s.w += v.w;
    }
    float mx = fmaxf(fmaxf(s.x, s.y), fmaxf(s.z, s.w));
#pragma unroll
    for (int d = 1; d < 64; d <<= 1) mx = fmaxf(mx, __shfl_xor(mx, d));
    float e0 = expf(s.x - mx), e1 = expf(s.y - mx), e2 = expf(s.z - mx), e3 = expf(s.w - mx);
    float sm = e0 + e1 + e2 + e3;
#pragma unroll
    for (int d = 1; d < 64; d <<= 1) sm += __shfl_xor(sm, d);
    float r = 1.f / sm;
    u16t* dst = pout + (size_t)row * 256 + l * 4;
    *(ushort4*)dst = make_ushort4(f2bf(e0 * r), f2bf(e1 * r), f2bf(e2 * r), f2bf(e3 * r));
}

// ---------------- K5: y = p . g  (tile 64n x 256d, BK=64) --------------------
__global__ void __launch_bounds__(256) k_pv(
    const u16t* __restrict__ pin, const u16t* __restrict__ g, u16t* __restrict__ y)
{
    __shared__ u16t gl[64 * 258];
    int blk = blockIdx.x;
    int dt = blk & 31, nt = (blk >> 5) & 3, b = blk >> 7;
    int n0 = nt * 64, d0 = dt * 256;
    int t = threadIdx.x, w = t >> 6, l = t & 63, lr = l & 15, lg = l >> 4;
    int wd = w * 64;
    f32x4 acc[4][4];
#pragma unroll
    for (int i = 0; i < 4; ++i)
#pragma unroll
        for (int j = 0; j < 4; ++j) acc[i][j] = (f32x4){0.f, 0.f, 0.f, 0.f};

    for (int kk = 0; kk < 4; ++kk) {
        __syncthreads();
        {   // stage g tile [64 m][256 d] -> [m][258]
            int mloc = t >> 2, part = t & 3;
            const u16t* src = g + ((size_t)b * 256 + kk * 64 + mloc) * 8192 + d0 + part * 8;
            u16t* dst = gl + mloc * 258 + part * 8;
#pragma unroll
            for (int i = 0; i < 8; ++i) {
                s16x8 v = *(const s16x8*)(src + i * 32);
                ushort2* d2 = (ushort2*)(dst + i * 32);
                d2[0] = make_ushort2((u16t)v[0], (u16t)v[1]);
                d2[1] = make_ushort2((u16t)v[2], (u16t)v[3]);
                d2[2] = make_ushort2((u16t)v[4], (u16t)v[5]);
                d2[3] = make_ushort2((u16t)v[6], (u16t)v[7]);
            }
        }
        __syncthreads();
#pragma unroll
        for (int kf = 0; kf < 2; ++kf) {
            s16x8 a[4];
#pragma unroll
            for (int rt = 0; rt < 4; ++rt)
                a[rt] = *(const s16x8*)(pin + ((size_t)b * 256 + n0 + rt * 16 + lr) * 256
                                        + kk * 64 + kf * 32 + lg * 8);
#pragma unroll
            for (int ct = 0; ct < 4; ++ct) {
                s16x8 bf = gather8(gl + (kf * 32 + lg * 8) * 258 + wd + ct * 16 + lr, 258);
#pragma unroll
                for (int rt = 0; rt < 4; ++rt)
                    acc[rt][ct] = MFMA(a[rt], bf, acc[rt][ct]);
            }
        }
    }
    u16t* yb = y + ((size_t)b * 256 + n0) * 8192 + d0 + wd;
#pragma unroll
    for (int rt = 0; rt < 4; ++rt)
#pragma unroll
        for (int r = 0; r < 4; ++r) {
            int nn = rt * 16 + lg * 4 + r;
#pragma unroll
            for (int ct = 0; ct < 4; ++ct)
                yb[(size_t)nn * 8192 + ct * 16 + lr] = f2bf(acc[rt][ct][r]);
        }
}

// ---------------- K6: w_y = y . w_w + w_b, pixel-major bf16 + BN stats -------
// one token / WG (128 thr, 2 waves split o); D[s][o], A = y from LDS [c][66]
__global__ void __launch_bounds__(128) k_wconv(
    const u16t* __restrict__ y, const u16t* __restrict__ wb, const float* __restrict__ w_b,
    u16t* __restrict__ wy, float* __restrict__ stats)
{
    __shared__ u16t yl[32 * 66];
    int blk = blockIdx.x;
    int b = blk >> 8, n = blk & 255;
    int t = threadIdx.x, w = t >> 6, l = t & 63, lr = l & 15, lg = l >> 4;
    int wo = w * 128;
    const u16t* wcv = wb + 163840;
    const u16t* yb = y + ((size_t)b * 256 + n) * 8192;
    f32x4 acc[4][8];
#pragma unroll
    for (int i = 0; i < 4; ++i)
#pragma unroll
        for (int j = 0; j < 8; ++j) acc[i][j] = (f32x4){0.f, 0.f, 0.f, 0.f};

    for (int kk = 0; kk < 4; ++kk) {
        __syncthreads();
        {   // stage 32c x 64s (2048 el); thread: 16 consecutive el
            const u16t* src = yb + kk * 2048 + t * 16;
            int c = t >> 2, s = (t & 3) * 16;
            u16t* dst = yl + c * 66 + s;
            s16x8 v0 = *(const s16x8*)src;
            s16x8 v1 = *(const s16x8*)(src + 8);
            ushort2* d2 = (ushort2*)dst;
            d2[0] = make_ushort2((u16t)v0[0], (u16t)v0[1]);
            d2[1] = make_ushort2((u16t)v0[2], (u16t)v0[3]);
            d2[2] = make_ushort2((u16t)v0[4], (u16t)v0[5]);
            d2[3] = make_ushort2((u16t)v0[6], (u16t)v0[7]);
            d2[4] = make_ushort2((u16t)v1[0], (u16t)v1[1]);
            d2[5] = make_ushort2((u16t)v1[2], (u16t)v1[3]);
            d2[6] = make_ushort2((u16t)v1[4], (u16t)v1[5]);
            d2[7] = make_ushort2((u16t)v1[6], (u16t)v1[7]);
        }
        __syncthreads();
        s16x8 a[4];
#pragma unroll
        for (int rt = 0; rt < 4; ++rt)
            a[rt] = gather8(yl + (lg * 8) * 66 + rt * 16 + lr, 66);
#pragma unroll
        for (int ct = 0; ct < 8; ++ct) {
            int o = wo + ct * 16 + lr;
            s16x8 bf = *(const s16x8*)(wcv + o * 128 + kk * 32 + lg * 8);
#pragma unroll
            for (int rt = 0; rt < 4; ++rt)
                acc[rt][ct] = MFMA(a[rt], bf, acc[rt][ct]);
        }
    }
    u16t* wyb = wy + ((size_t)b * 16384 + n * 64) * 256;
    float s1[8], s2[8];
#pragma unroll
    for (int ct = 0; ct < 8; ++ct) { s1[ct] = 0.f; s2[ct] = 0.f; }
#pragma unroll
    for (int ct = 0; ct < 8; ++ct) {
        int o = wo + ct * 16 + lr;
        float bv = w_b[o];
#pragma unroll
        for (int rt = 0; rt < 4; ++rt)
#pragma unroll
            for (int r = 0; r < 4; ++r) {
                float v = acc[rt][ct][r] + bv;
                int s = rt * 16 + lg * 4 + r;
                wyb[(size_t)s * 256 + o] = f2bf(v);
                s1[ct] += v; s2[ct] += v * v;
            }
    }
#pragma unroll
    for (int ct = 0; ct < 8; ++ct) {
        s1[ct] += __shfl_xor(s1[ct], 16); s1[ct] += __shfl_xor(s1[ct], 32);
        s2[ct] += __shfl_xor(s2[ct], 16); s2[ct] += __shfl_xor(s2[ct], 32);
        if (lg == 0) {
            int o = wo + ct * 16 + lr;
            atomicAdd(&stats[o], s1[ct]);
            atomicAdd(&stats[256 + o], s2[ct]);
        }
    }
}

// ---------------- K7: BN + residual, fp32 out --------------------------------
// per WG: 4-token strip, two 2-token phases via 64KB LDS [128 pix][256 o] with
// o-swizzle os = (o + (pix>>3)*8) & 255 to kill bank conflicts on strided reads.
__global__ void __launch_bounds__(256) k_final(
    const u16t* __restrict__ wy, const float* __restrict__ x, const float* __restrict__ stats,
    const float* __restrict__ gamma, const float* __restrict__ beta, float* __restrict__ out)
{
    __shared__ u16t lds[128 * 256];
    int blk = blockIdx.x;
    int b = blk >> 6, strip = blk & 63;
    int pi = strip >> 2, pjq = strip & 3;
    int t = threadIdx.x;
    int wh = t & 1, u = (t >> 1) & 7;
    int h0 = pi * 8;
    const float rcpN = 1.f / 131072.f;

    for (int ph2 = 0; ph2 < 2; ++ph2) {
        int n0 = pi * 16 + pjq * 4 + ph2 * 2;
        const u16t* src = wy + ((size_t)b * 16384 + n0 * 64) * 256;
        __syncthreads();
#pragma unroll
        for (int i = 0; i < 16; ++i) {
            int el = i * 2048 + t * 8;
            int pl = el >> 8;
            int oo = (t & 31) * 8;
            int os = (oo + (pl >> 3) * 8) & 255;
            *(s16x8*)(lds + pl * 256 + os) = *(const s16x8*)(src + el);
        }
        __syncthreads();
        int w0 = pjq * 32 + ph2 * 16;
        int shift2 = (wh * 8 + u) * 8;   // = (pixloc>>3)*8 for this thread's row
#pragma unroll
        for (int i = 0; i < 16; ++i) {
            int oc = (t >> 4) + i * 16;
            float mm = stats[oc] * rcpN;
            float vv = stats[256 + oc] * rcpN - mm * mm;
            float aa = gamma[oc] * rsqrtf(vv + 1e-5f);
            float cc = beta[oc] - mm * aa;
            const u16t* lrow = lds + (wh * 64 + u * 8) * 256 + ((oc + shift2) & 255);
            size_t xidx = (((size_t)b * 256 + oc) * 128 + h0 + u) * 128 + w0 + wh * 8;
            float4 x0 = *(const float4*)(x + xidx);
            float4 x1 = *(const float4*)(x + xidx + 4);
            float4 o0, o1;
            o0.x = bf2f(lrow[0 * 256]) * aa + cc + x0.x;
            o0.y = bf2f(lrow[1 * 256]) * aa + cc + x0.y;
            o0.z = bf2f(lrow[2 * 256]) * aa + cc + x0.z;
            o0.w = bf2f(lrow[3 * 256]) * aa + cc + x0.w;
            o1.x = bf2f(lrow[4 * 256]) * aa + cc + x1.x;
            o1.y = bf2f(lrow[5 * 256]) * aa + cc + x1.y;
            o1.z = bf2f(lrow[6 * 256]) * aa + cc + x1.z;
            o1.w = bf2f(lrow[7 * 256]) * aa + cc + x1.w;
            *(float4*)(out + xidx) = o0;
            *(float4*)(out + xidx + 4) = o1;
        }
    }
}

// ---------------------------------------------------------------------------
extern "C" void kernel_launch(void* const* d_in, const int* in_sizes, int n_in,
                              void* d_out, int out_size, void* d_ws, size_t ws_size,
                              hipStream_t stream)
{
    (void)in_sizes; (void)n_in; (void)out_size;
    const float* x    = (const float*)d_in[0];
    const float* g_w  = (const float*)d_in[1];
    const float* g_b  = (const float*)d_in[2];
    const float* t_w  = (const float*)d_in[3];
    const float* t_b  = (const float*)d_in[4];
    const float* p_w  = (const float*)d_in[5];
    const float* p_b  = (const float*)d_in[6];
    const float* w_w  = (const float*)d_in[7];
    const float* w_b  = (const float*)d_in[8];
    const float* bn_g = (const float*)d_in[9];
    const float* bn_b = (const float*)d_in[10];

    // ws layout (bytes): g 0..33.5M | fp 33.5M..67.1M (aliased by wy 33.5M..100.7M)
    //                    p 100.7M | stats | wb ; total ~102.1MB
    const size_t G_OFF  = 0;
    const size_t FP_OFF = 33554432;
    const size_t WY_OFF = 33554432;          // aliases FP (dead after softmax)
    const size_t P_OFF  = 100663296;
    const size_t ST_OFF = 101711872;
    const size_t WB_OFF = 101713920;
    const size_t NEEDED = 102107136;
    if (ws_size < NEEDED) return;            // diagnostic: absmax will equal max|ref|

    char* ws = (char*)d_ws;
    u16t*  g_buf = (u16t*)(ws + G_OFF);
    float* fp    = (float*)(ws + FP_OFF);
    u16t*  wy    = (u16t*)(ws + WY_OFF);
    u16t*  p_buf = (u16t*)(ws + P_OFF);
    float* stats = (float*)(ws + ST_OFF);
    u16t*  wb    = (u16t*)(ws + WB_OFF);

    float* th_g = (float*)d_out;             // theta fp32 (16.78M floats)
    float* ph_g = th_g + 16777216;           // phi fp32
    u16t*  y_buf = (u16t*)d_out;             // y bf16 (reuses d_out after QK)

    k_prep<<<128, 256, 0, stream>>>(g_w, t_w, p_w, w_w, wb);
    hipMemsetAsync(stats, 0, 2048, stream);
    k_proj<<<256, 512, 0, stream>>>(x, wb, t_b, p_b, g_b, th_g, ph_g, g_buf);
    k_qk<<<512, 256, 0, stream>>>(th_g, ph_g, fp);
    k_softmax<<<512, 256, 0, stream>>>(fp, p_buf);
    k_pv<<<1024, 256, 0, stream>>>(p_buf, g_buf, y_buf);
    k_wconv<<<2048, 128, 0, stream>>>(y_buf, wb, w_b, wy, stats);
    k_final<<<512, 256, 0, stream>>>(wy, x, stats, bn_g, bn_b, (float*)d_out);
}

// Round 5
// 382.740 us; speedup vs baseline: 1.3672x; 1.3672x over previous
//
#include <hip/hip_runtime.h>
#include <stdint.h>

// ---------------------------------------------------------------------------
// NonLocalBlockND: B=8, C_IN=256, C_INTER=128, H=W=128, P=16 -> tokens 256/batch,
// token dim D = 128*64 = 8192 (d = c*64 + s, s = u*8+v within 8x8 patch).
// Pipeline:
//   K1 prep   : weights -> bf16; theta/phi/g pre-swizzled into MFMA A-fragment
//               order; hi+lo split for theta/phi
//   K2 proj   : one token/block (grid 2048, XCD batch-chunked), x staged hi/lo
//               in 64KB LDS; SINGLE merged pass: per (kk,ct) 2 ds_read_b128
//               feed 8 MFMAs (theta 3-term, phi 3-term, g 2-term). Weights
//               streamed per-kk (short-lived regs -> no spill).
//   K3 qk     : f = theta . phi (3-term bf16 split MFMA), K-split 16, partials in ws
//   K4 softmax: reduce partials, softmax rows -> p (bf16)
//   K5 pv     : y = p . g (bf16 MFMA) -> d_out (theta/phi dead)
//   K6 wconv  : w_y = y . w_w + w_b (bf16 MFMA), pixel-major bf16 + BN stats atomics
//   K7 final  : out = (w_y - mean)*rsqrt(var+eps)*gamma + beta + x   (fp32)
// ---------------------------------------------------------------------------

typedef unsigned short u16t;
typedef short s16x8 __attribute__((ext_vector_type(8)));
typedef float f32x4 __attribute__((ext_vector_type(4)));
typedef uint32_t u32x4 __attribute__((ext_vector_type(4)));

#define DEV __device__ __forceinline__

DEV u16t f2bf(float f) {
    union { float f; uint32_t u; } v; v.f = f;
    return (u16t)((v.u + 0x7FFFu + ((v.u >> 16) & 1u)) >> 16);
}
DEV float bf2f(u16t h) {
    union { uint32_t u; float f; } v; v.u = ((uint32_t)h) << 16; return v.f;
}
DEV f32x4 MFMA(s16x8 a, s16x8 b, f32x4 c) {
    return __builtin_amdgcn_mfma_f32_16x16x32_bf16(a, b, c, 0, 0, 0);
}
DEV s16x8 gather8(const u16t* base, int stride) {
    s16x8 r;
#pragma unroll
    for (int j = 0; j < 8; ++j) r[j] = (short)base[j * stride];
    return r;
}

// ---------------- K1: weight prep -> bf16 ------------------------------------
// th/tl/ph/pl/g stored A-fragment-swizzled: for o in [0,128), c in [0,256):
//   fi = ((o>>4)*8 + (c>>5))*512 + (((c>>3)&3)*16 + (o&15))*8 + (c&7)
// so the A-load for (rt,kk) is 64 lanes x 16B contiguous.
// wcv (w_w, [256][128]) kept flat at 163840.
__global__ void __launch_bounds__(256) k_prep(
    const float* __restrict__ gw, const float* __restrict__ tw,
    const float* __restrict__ pw, const float* __restrict__ ww,
    u16t* __restrict__ wb)
{
    int i = blockIdx.x * 256 + threadIdx.x;
    if (i >= 32768) return;
    int o = i >> 8, c = i & 255;
    int fi = ((o >> 4) * 8 + (c >> 5)) * 512 + (((c >> 3) & 3) * 16 + (o & 15)) * 8 + (c & 7);
    float t = tw[i], p = pw[i];
    u16t th = f2bf(t); u16t tl = f2bf(t - bf2f(th));
    u16t ph = f2bf(p); u16t pl = f2bf(p - bf2f(ph));
    wb[fi] = th; wb[32768 + fi] = tl;
    wb[65536 + fi] = ph; wb[98304 + fi] = pl;
    wb[131072 + fi] = f2bf(gw[i]);
    wb[163840 + i] = f2bf(ww[i]);
}

// ---------------- K2: projections, merged single pass -----------------------
// One token / WG (256 thr = 4 waves). x (64 pix x 256 c) staged hi/lo bf16 in
// 64KB LDS, [pix][256c] with octet rotation swizzle oct'=(oct+pix)&31.
// Wave w owns o in [32w,32w+32) for ALL THREE projections. Per (kk,ct):
// 2 ds_read_b128 (bh,bl) -> 8 MFMA. Weight frags loaded per-kk (transient).
__global__ void __launch_bounds__(256, 2) k_proj(
    const float* __restrict__ x, const u16t* __restrict__ wb,
    const float* __restrict__ tb, const float* __restrict__ pb, const float* __restrict__ gbias,
    float* __restrict__ out_t, float* __restrict__ out_p, u16t* __restrict__ out_g)
{
    __shared__ u16t xh[64 * 256];
    __shared__ u16t xl[64 * 256];
    int phys = blockIdx.x;
    int blk = ((phys & 7) << 8) | (phys >> 3);   // XCD chunking: one batch per XCD
    int b = blk >> 8, n = blk & 255;
    int pi = n >> 4, pj = n & 15;
    int t = threadIdx.x;
    int w = t >> 6, l = t & 63, lr = l & 15, lg = l >> 4;

    // ---- stage x hi/lo into LDS: lane = pixel, wave w covers octets [8w,8w+8)
    {
        int p = l;
        const float* xb = x + (((size_t)b * 256) * 128 + pi * 8 + (p >> 3)) * 128 + pj * 8 + (p & 7);
#pragma unroll
        for (int i = 0; i < 8; ++i) {
            int octet = w * 8 + i;
            float v[8];
#pragma unroll
            for (int j = 0; j < 8; ++j) v[j] = xb[(size_t)(octet * 8 + j) * 16384];
            u32x4 hv, lv;
#pragma unroll
            for (int j = 0; j < 8; j += 2) {
                uint32_t u0 = __float_as_uint(v[j]), u1 = __float_as_uint(v[j + 1]);
                hv[j >> 1] = (u0 >> 16) | (u1 & 0xFFFF0000u);          // truncation hi
                float f0 = v[j]     - __uint_as_float(u0 & 0xFFFF0000u);
                float f1 = v[j + 1] - __uint_as_float(u1 & 0xFFFF0000u);
                lv[j >> 1] = (uint32_t)f2bf(f0) | ((uint32_t)f2bf(f1) << 16);  // RN lo
            }
            int oct2 = (octet + p) & 31;
            *(s16x8*)(xh + p * 256 + oct2 * 8) = __builtin_bit_cast(s16x8, hv);
            *(s16x8*)(xl + p * 256 + oct2 * 8) = __builtin_bit_cast(s16x8, lv);
        }
    }
    __syncthreads();

    const u16t* Th = wb;          const u16t* Tl = wb + 32768;
    const u16t* Ph = wb + 65536;  const u16t* Pl = wb + 98304;
    const u16t* Gh = wb + 131072;

    f32x4 aT[2][4], aP[2][4], aG[2][4];
#pragma unroll
    for (int q = 0; q < 2; ++q)
#pragma unroll
        for (int ct = 0; ct < 4; ++ct) {
            aT[q][ct] = (f32x4){0.f, 0.f, 0.f, 0.f};
            aP[q][ct] = (f32x4){0.f, 0.f, 0.f, 0.f};
            aG[q][ct] = (f32x4){0.f, 0.f, 0.f, 0.f};
        }

#pragma unroll
    for (int kk = 0; kk < 8; ++kk) {
        s16x8 th_[2], tl_[2], ph_[2], pl_[2], gh_[2];
#pragma unroll
        for (int q = 0; q < 2; ++q) {
            int rt = 2 * w + q;
            size_t off = (size_t)((rt * 8 + kk) * 64 + l) * 8;
            th_[q] = *(const s16x8*)(Th + off);
            tl_[q] = *(const s16x8*)(Tl + off);
            ph_[q] = *(const s16x8*)(Ph + off);
            pl_[q] = *(const s16x8*)(Pl + off);
            gh_[q] = *(const s16x8*)(Gh + off);
        }
#pragma unroll
        for (int ct = 0; ct < 4; ++ct) {
            int pr = ct * 16 + lr;
            int rot = (kk * 4 + lg + pr) & 31;
            s16x8 bh = *(const s16x8*)(xh + pr * 256 + rot * 8);
            s16x8 bl = *(const s16x8*)(xl + pr * 256 + rot * 8);
#pragma unroll
            for (int q = 0; q < 2; ++q) {
                aT[q][ct] = MFMA(th_[q], bh, aT[q][ct]);
                aT[q][ct] = MFMA(tl_[q], bh, aT[q][ct]);
                aT[q][ct] = MFMA(th_[q], bl, aT[q][ct]);
                aP[q][ct] = MFMA(ph_[q], bh, aP[q][ct]);
                aP[q][ct] = MFMA(pl_[q], bh, aP[q][ct]);
                aP[q][ct] = MFMA(ph_[q], bl, aP[q][ct]);
                aG[q][ct] = MFMA(gh_[q], bh, aG[q][ct]);
                aG[q][ct] = MFMA(gh_[q], bl, aG[q][ct]);
            }
        }
    }

    // ---- epilogue: D row=(lg*4+r) -> o within 16-tile ; col=ct*16+lr -> s
    size_t obase = ((size_t)b * 256 + n) * 8192;
#pragma unroll
    for (int q = 0; q < 2; ++q)
#pragma unroll
        for (int r = 0; r < 4; ++r) {
            int o = w * 32 + q * 16 + lg * 4 + r;
            float bvT = tb[o], bvP = pb[o], bvG = gbias[o];
#pragma unroll
            for (int ct = 0; ct < 4; ++ct) {
                int s = ct * 16 + lr;
                out_t[obase + (size_t)o * 64 + s] = aT[q][ct][r] + bvT;
                out_p[obase + (size_t)o * 64 + s] = aP[q][ct][r] + bvP;
                out_g[obase + (size_t)o * 64 + s] = f2bf(aG[q][ct][r] + bvG);
            }
        }
}

// ---------------- K3: QK^T, 3-term split, K-split 16 -------------------------
// grid 512: mt=blk&1, nt=(blk>>1)&1, b=(blk>>2)&7, kc=blk>>5 ; tile 128x128, BK=32
__global__ void __launch_bounds__(256) k_qk(
    const float* __restrict__ th_g, const float* __restrict__ ph_g, float* __restrict__ fp)
{
    __shared__ u16t th[128 * 40], tl[128 * 40], ph[128 * 40], pl[128 * 40];
    int blk = blockIdx.x;
    int mt = blk & 1, nt = (blk >> 1) & 1, b = (blk >> 2) & 7, kc = blk >> 5;
    int n0 = nt * 128, m0 = mt * 128;
    int t = threadIdx.x;
    int w = t >> 6, l = t & 63, lr = l & 15, lg = l >> 4;
    int wn = (w & 1) * 64, wm = (w >> 1) * 64;
    f32x4 acc[4][4];
#pragma unroll
    for (int i = 0; i < 4; ++i)
#pragma unroll
        for (int j = 0; j < 4; ++j) acc[i][j] = (f32x4){0.f, 0.f, 0.f, 0.f};

    const float* tsrc = th_g + ((size_t)b * 256 + n0) * 8192 + kc * 512;
    const float* psrc = ph_g + ((size_t)b * 256 + m0) * 8192 + kc * 512;

    for (int kk = 0; kk < 16; ++kk) {
        __syncthreads();
        // stage 256 rows (theta 0-127, phi 128-255) x 32 d, 8 threads/row
#pragma unroll
        for (int i = 0; i < 8; ++i) {
            int row = i * 32 + (t >> 3);
            int q = t & 7;
            int r7 = row & 127;
            const float* sp = ((row < 128) ? (tsrc + (size_t)r7 * 8192)
                                           : (psrc + (size_t)r7 * 8192)) + kk * 32 + q * 4;
            float4 v = *(const float4*)sp;
            u16t* dh = ((row < 128) ? th : ph) + r7 * 40 + q * 4;
            u16t* dl = ((row < 128) ? tl : pl) + r7 * 40 + q * 4;
            u16t h0 = f2bf(v.x), h1 = f2bf(v.y), h2 = f2bf(v.z), h3 = f2bf(v.w);
            *(ushort2*)dh       = make_ushort2(h0, h1);
            *(ushort2*)(dh + 2) = make_ushort2(h2, h3);
            *(ushort2*)dl       = make_ushort2(f2bf(v.x - bf2f(h0)), f2bf(v.y - bf2f(h1)));
            *(ushort2*)(dl + 2) = make_ushort2(f2bf(v.z - bf2f(h2)), f2bf(v.w - bf2f(h3)));
        }
        __syncthreads();
        s16x8 a_h[4], a_l[4], b_h[4], b_l[4];
#pragma unroll
        for (int rt = 0; rt < 4; ++rt) {
            int row = wn + rt * 16 + lr;
            a_h[rt] = *(const s16x8*)(th + row * 40 + lg * 8);
            a_l[rt] = *(const s16x8*)(tl + row * 40 + lg * 8);
        }
#pragma unroll
        for (int ct = 0; ct < 4; ++ct) {
            int row = wm + ct * 16 + lr;
            b_h[ct] = *(const s16x8*)(ph + row * 40 + lg * 8);
            b_l[ct] = *(const s16x8*)(pl + row * 40 + lg * 8);
        }
#pragma unroll
        for (int rt = 0; rt < 4; ++rt)
#pragma unroll
            for (int ct = 0; ct < 4; ++ct) {
                acc[rt][ct] = MFMA(a_h[rt], b_h[ct], acc[rt][ct]);
                acc[rt][ct] = MFMA(a_l[rt], b_h[ct], acc[rt][ct]);
                acc[rt][ct] = MFMA(a_h[rt], b_l[ct], acc[rt][ct]);
            }
    }
    float* dst = fp + (size_t)kc * 524288 + ((size_t)b * 256 + n0 + wn) * 256 + m0 + wm;
#pragma unroll
    for (int rt = 0; rt < 4; ++rt)
#pragma unroll
        for (int r = 0; r < 4; ++r) {
            int nn = rt * 16 + lg * 4 + r;
#pragma unroll
            for (int ct = 0; ct < 4; ++ct)
                dst[(size_t)nn * 256 + ct * 16 + lr] = acc[rt][ct][r];
        }
}

// ---------------- K4: reduce partials + row softmax -> p bf16 ---------------
__global__ void __launch_bounds__(256) k_softmax(
    const float* __restrict__ fp, u16t* __restrict__ pout)
{
    int row = blockIdx.x * 4 + (threadIdx.x >> 6);
    int l = threadIdx.x & 63;
    const float* src = fp + (size_t)row * 256 + l * 4;
    float4 s = {0.f, 0.f, 0.f, 0.f};
#pragma unroll
    for (int kc = 0; kc < 16; ++kc) {
        float4 v = *(const float4*)(src + (size_t)kc * 524288);
        s.x += v.x; s.y += v.y; s.z += v.z; s.w += v.w;
    }
    float mx = fmaxf(fmaxf(s.x, s.y), fmaxf(s.z, s.w));
#pragma unroll
    for (int d = 1; d < 64; d <<= 1) mx = fmaxf(mx, __shfl_xor(mx, d));
    float e0 = expf(s.x - mx), e1 = expf(s.y - mx), e2 = expf(s.z - mx), e3 = expf(s.w - mx);
    float sm = e0 + e1 + e2 + e3;
#pragma unroll
    for (int d = 1; d < 64; d <<= 1) sm += __shfl_xor(sm, d);
    float r = 1.f / sm;
    u16t* dst = pout + (size_t)row * 256 + l * 4;
    *(ushort4*)dst = make_ushort4(f2bf(e0 * r), f2bf(e1 * r), f2bf(e2 * r), f2bf(e3 * r));
}

// ---------------- K5: y = p . g  (tile 64n x 256d, BK=64) --------------------
__global__ void __launch_bounds__(256) k_pv(
    const u16t* __restrict__ pin, const u16t* __restrict__ g, u16t* __restrict__ y)
{
    __shared__ u16t gl[64 * 258];
    int blk = blockIdx.x;
    int dt = blk & 31, nt = (blk >> 5) & 3, b = blk >> 7;
    int n0 = nt * 64, d0 = dt * 256;
    int t = threadIdx.x, w = t >> 6, l = t & 63, lr = l & 15, lg = l >> 4;
    int wd = w * 64;
    f32x4 acc[4][4];
#pragma unroll
    for (int i = 0; i < 4; ++i)
#pragma unroll
        for (int j = 0; j < 4; ++j) acc[i][j] = (f32x4){0.f, 0.f, 0.f, 0.f};

    for (int kk = 0; kk < 4; ++kk) {
        __syncthreads();
        {   // stage g tile [64 m][256 d] -> [m][258]
            int mloc = t >> 2, part = t & 3;
            const u16t* src = g + ((size_t)b * 256 + kk * 64 + mloc) * 8192 + d0 + part * 8;
            u16t* dst = gl + mloc * 258 + part * 8;
#pragma unroll
            for (int i = 0; i < 8; ++i) {
                s16x8 v = *(const s16x8*)(src + i * 32);
                ushort2* d2 = (ushort2*)(dst + i * 32);
                d2[0] = make_ushort2((u16t)v[0], (u16t)v[1]);
                d2[1] = make_ushort2((u16t)v[2], (u16t)v[3]);
                d2[2] = make_ushort2((u16t)v[4], (u16t)v[5]);
                d2[3] = make_ushort2((u16t)v[6], (u16t)v[7]);
            }
        }
        __syncthreads();
#pragma unroll
        for (int kf = 0; kf < 2; ++kf) {
            s16x8 a[4];
#pragma unroll
            for (int rt = 0; rt < 4; ++rt)
                a[rt] = *(const s16x8*)(pin + ((size_t)b * 256 + n0 + rt * 16 + lr) * 256
                                        + kk * 64 + kf * 32 + lg * 8);
#pragma unroll
            for (int ct = 0; ct < 4; ++ct) {
                s16x8 bf = gather8(gl + (kf * 32 + lg * 8) * 258 + wd + ct * 16 + lr, 258);
#pragma unroll
                for (int rt = 0; rt < 4; ++rt)
                    acc[rt][ct] = MFMA(a[rt], bf, acc[rt][ct]);
            }
        }
    }
    u16t* yb = y + ((size_t)b * 256 + n0) * 8192 + d0 + wd;
#pragma unroll
    for (int rt = 0; rt < 4; ++rt)
#pragma unroll
        for (int r = 0; r < 4; ++r) {
            int nn = rt * 16 + lg * 4 + r;
#pragma unroll
            for (int ct = 0; ct < 4; ++ct)
                yb[(size_t)nn * 8192 + ct * 16 + lr] = f2bf(acc[rt][ct][r]);
        }
}

// ---------------- K6: w_y = y . w_w + w_b, pixel-major bf16 + BN stats -------
// one token / WG (128 thr, 2 waves split o); D[s][o], A = y from LDS [c][66]
__global__ void __launch_bounds__(128) k_wconv(
    const u16t* __restrict__ y, const u16t* __restrict__ wb, const float* __restrict__ w_b,
    u16t* __restrict__ wy, float* __restrict__ stats)
{
    __shared__ u16t yl[32 * 66];
    int blk = blockIdx.x;
    int b = blk >> 8, n = blk & 255;
    int t = threadIdx.x, w = t >> 6, l = t & 63, lr = l & 15, lg = l >> 4;
    int wo = w * 128;
    const u16t* wcv = wb + 163840;
    const u16t* yb = y + ((size_t)b * 256 + n) * 8192;
    f32x4 acc[4][8];
#pragma unroll
    for (int i = 0; i < 4; ++i)
#pragma unroll
        for (int j = 0; j < 8; ++j) acc[i][j] = (f32x4){0.f, 0.f, 0.f, 0.f};

    for (int kk = 0; kk < 4; ++kk) {
        __syncthreads();
        {   // stage 32c x 64s (2048 el); thread: 16 consecutive el
            const u16t* src = yb + kk * 2048 + t * 16;
            int c = t >> 2, s = (t & 3) * 16;
            u16t* dst = yl + c * 66 + s;
            s16x8 v0 = *(const s16x8*)src;
            s16x8 v1 = *(const s16x8*)(src + 8);
            ushort2* d2 = (ushort2*)dst;
            d2[0] = make_ushort2((u16t)v0[0], (u16t)v0[1]);
            d2[1] = make_ushort2((u16t)v0[2], (u16t)v0[3]);
            d2[2] = make_ushort2((u16t)v0[4], (u16t)v0[5]);
            d2[3] = make_ushort2((u16t)v0[6], (u16t)v0[7]);
            d2[4] = make_ushort2((u16t)v1[0], (u16t)v1[1]);
            d2[5] = make_ushort2((u16t)v1[2], (u16t)v1[3]);
            d2[6] = make_ushort2((u16t)v1[4], (u16t)v1[5]);
            d2[7] = make_ushort2((u16t)v1[6], (u16t)v1[7]);
        }
        __syncthreads();
        s16x8 a[4];
#pragma unroll
        for (int rt = 0; rt < 4; ++rt)
            a[rt] = gather8(yl + (lg * 8) * 66 + rt * 16 + lr, 66);
#pragma unroll
        for (int ct = 0; ct < 8; ++ct) {
            int o = wo + ct * 16 + lr;
            s16x8 bf = *(const s16x8*)(wcv + o * 128 + kk * 32 + lg * 8);
#pragma unroll
            for (int rt = 0; rt < 4; ++rt)
                acc[rt][ct] = MFMA(a[rt], bf, acc[rt][ct]);
        }
    }
    u16t* wyb = wy + ((size_t)b * 16384 + n * 64) * 256;
    float s1[8], s2[8];
#pragma unroll
    for (int ct = 0; ct < 8; ++ct) { s1[ct] = 0.f; s2[ct] = 0.f; }
#pragma unroll
    for (int ct = 0; ct < 8; ++ct) {
        int o = wo + ct * 16 + lr;
        float bv = w_b[o];
#pragma unroll
        for (int rt = 0; rt < 4; ++rt)
#pragma unroll
            for (int r = 0; r < 4; ++r) {
                float v = acc[rt][ct][r] + bv;
                int s = rt * 16 + lg * 4 + r;
                wyb[(size_t)s * 256 + o] = f2bf(v);
                s1[ct] += v; s2[ct] += v * v;
            }
    }
#pragma unroll
    for (int ct = 0; ct < 8; ++ct) {
        s1[ct] += __shfl_xor(s1[ct], 16); s1[ct] += __shfl_xor(s1[ct], 32);
        s2[ct] += __shfl_xor(s2[ct], 16); s2[ct] += __shfl_xor(s2[ct], 32);
        if (lg == 0) {
            int o = wo + ct * 16 + lr;
            atomicAdd(&stats[o], s1[ct]);
            atomicAdd(&stats[256 + o], s2[ct]);
        }
    }
}

// ---------------- K7: BN + residual, fp32 out --------------------------------
// per WG: 4-token strip, two 2-token phases via 64KB LDS [128 pix][256 o] with
// o-swizzle os = (o + (pix>>3)*8) & 255 to kill bank conflicts on strided reads.
__global__ void __launch_bounds__(256) k_final(
    const u16t* __restrict__ wy, const float* __restrict__ x, const float* __restrict__ stats,
    const float* __restrict__ gamma, const float* __restrict__ beta, float* __restrict__ out)
{
    __shared__ u16t lds[128 * 256];
    int blk = blockIdx.x;
    int b = blk >> 6, strip = blk & 63;
    int pi = strip >> 2, pjq = strip & 3;
    int t = threadIdx.x;
    int wh = t & 1, u = (t >> 1) & 7;
    int h0 = pi * 8;
    const float rcpN = 1.f / 131072.f;

    for (int ph2 = 0; ph2 < 2; ++ph2) {
        int n0 = pi * 16 + pjq * 4 + ph2 * 2;
        const u16t* src = wy + ((size_t)b * 16384 + n0 * 64) * 256;
        __syncthreads();
#pragma unroll
        for (int i = 0; i < 16; ++i) {
            int el = i * 2048 + t * 8;
            int pl = el >> 8;
            int oo = (t & 31) * 8;
            int os = (oo + (pl >> 3) * 8) & 255;
            *(s16x8*)(lds + pl * 256 + os) = *(const s16x8*)(src + el);
        }
        __syncthreads();
        int w0 = pjq * 32 + ph2 * 16;
        int shift2 = (wh * 8 + u) * 8;   // = (pixloc>>3)*8 for this thread's row
#pragma unroll
        for (int i = 0; i < 16; ++i) {
            int oc = (t >> 4) + i * 16;
            float mm = stats[oc] * rcpN;
            float vv = stats[256 + oc] * rcpN - mm * mm;
            float aa = gamma[oc] * rsqrtf(vv + 1e-5f);
            float cc = beta[oc] - mm * aa;
            const u16t* lrow = lds + (wh * 64 + u * 8) * 256 + ((oc + shift2) & 255);
            size_t xidx = (((size_t)b * 256 + oc) * 128 + h0 + u) * 128 + w0 + wh * 8;
            float4 x0 = *(const float4*)(x + xidx);
            float4 x1 = *(const float4*)(x + xidx + 4);
            float4 o0, o1;
            o0.x = bf2f(lrow[0 * 256]) * aa + cc + x0.x;
            o0.y = bf2f(lrow[1 * 256]) * aa + cc + x0.y;
            o0.z = bf2f(lrow[2 * 256]) * aa + cc + x0.z;
            o0.w = bf2f(lrow[3 * 256]) * aa + cc + x0.w;
            o1.x = bf2f(lrow[4 * 256]) * aa + cc + x1.x;
            o1.y = bf2f(lrow[5 * 256]) * aa + cc + x1.y;
            o1.z = bf2f(lrow[6 * 256]) * aa + cc + x1.z;
            o1.w = bf2f(lrow[7 * 256]) * aa + cc + x1.w;
            *(float4*)(out + xidx) = o0;
            *(float4*)(out + xidx + 4) = o1;
        }
    }
}

// ---------------------------------------------------------------------------
extern "C" void kernel_launch(void* const* d_in, const int* in_sizes, int n_in,
                              void* d_out, int out_size, void* d_ws, size_t ws_size,
                              hipStream_t stream)
{
    (void)in_sizes; (void)n_in; (void)out_size;
    const float* x    = (const float*)d_in[0];
    const float* g_w  = (const float*)d_in[1];
    const float* g_b  = (const float*)d_in[2];
    const float* t_w  = (const float*)d_in[3];
    const float* t_b  = (const float*)d_in[4];
    const float* p_w  = (const float*)d_in[5];
    const float* p_b  = (const float*)d_in[6];
    const float* w_w  = (const float*)d_in[7];
    const float* w_b  = (const float*)d_in[8];
    const float* bn_g = (const float*)d_in[9];
    const float* bn_b = (const float*)d_in[10];

    // ws layout (bytes): g 0..33.5M | fp 33.5M..67.1M (aliased by wy 33.5M..100.7M)
    //                    p 100.7M | stats | wb ; total ~102.1MB
    const size_t G_OFF  = 0;
    const size_t FP_OFF = 33554432;
    const size_t WY_OFF = 33554432;          // aliases FP (dead after softmax)
    const size_t P_OFF  = 100663296;
    const size_t ST_OFF = 101711872;
    const size_t WB_OFF = 101713920;
    const size_t NEEDED = 102107136;
    if (ws_size < NEEDED) return;            // diagnostic: absmax will equal max|ref|

    char* ws = (char*)d_ws;
    u16t*  g_buf = (u16t*)(ws + G_OFF);
    float* fp    = (float*)(ws + FP_OFF);
    u16t*  wy    = (u16t*)(ws + WY_OFF);
    u16t*  p_buf = (u16t*)(ws + P_OFF);
    float* stats = (float*)(ws + ST_OFF);
    u16t*  wb    = (u16t*)(ws + WB_OFF);

    float* th_g = (float*)d_out;             // theta fp32 (16.78M floats)
    float* ph_g = th_g + 16777216;           // phi fp32
    u16t*  y_buf = (u16t*)d_out;             // y bf16 (reuses d_out after QK)

    k_prep<<<128, 256, 0, stream>>>(g_w, t_w, p_w, w_w, wb);
    hipMemsetAsync(stats, 0, 2048, stream);
    k_proj<<<2048, 256, 0, stream>>>(x, wb, t_b, p_b, g_b, th_g, ph_g, g_buf);
    k_qk<<<512, 256, 0, stream>>>(th_g, ph_g, fp);
    k_softmax<<<512, 256, 0, stream>>>(fp, p_buf);
    k_pv<<<1024, 256, 0, stream>>>(p_buf, g_buf, y_buf);
    k_wconv<<<2048, 128, 0, stream>>>(y_buf, wb, w_b, wy, stats);
    k_final<<<512, 256, 0, stream>>>(wy, x, stats, bn_g, bn_b, (float*)d_out);
}